// Round 12
// baseline (58.157 us; speedup 1.0000x reference)
//
#include <hip/hip_runtime.h>
#include <hip/hip_bf16.h>

#define B_   2
#define L_   1024
#define D_   1024
#define H_   8
#define DV_  1536
#define HDV_ 12288          // H_*DV_
#define INV_L (1.0f/1024.0f)

// ws layout (floats):
//   vsum : [0, 2048)         2*1024 column sums of v
//   G    : [26624, 30720)    4*1024   order: b0p0, b0p1, b1p0, b1p1 (atomic acc)

// ---- K1: blocks [0,32) = vsum; block 32 = zero G; blocks [33,33+16384) = atten
__global__ void __launch_bounds__(256) k1(const float* __restrict__ v,
                                          float* __restrict__ vsum,
                                          const int* __restrict__ mask,
                                          float* __restrict__ atten,
                                          float* __restrict__ G) {
    int bx = blockIdx.x, t = threadIdx.x;
    if (bx < 32) {
        __shared__ float4 lds[16][16];
        int b  = bx >> 4;            // batch
        int s  = bx & 15;            // 64-column strip
        int c4 = t & 15;             // float4 column within strip
        int rg = t >> 4;             // 16 row-groups of 64 rows
        const float4* vp = (const float4*)(v + (size_t)b * L_ * D_)
                           + (size_t)s * 16 + c4;
        float4 acc = make_float4(0.f, 0.f, 0.f, 0.f);
        #pragma unroll 8
        for (int r = 0; r < 64; ++r) {
            float4 x = vp[(size_t)(rg * 64 + r) * (D_ / 4)];
            acc.x += x.x; acc.y += x.y; acc.z += x.z; acc.w += x.w;
        }
        lds[rg][c4] = acc;
        __syncthreads();
        if (t < 16) {                // t = c4
            float4 a = make_float4(0.f, 0.f, 0.f, 0.f);
            #pragma unroll
            for (int g = 0; g < 16; ++g) {
                float4 x = lds[g][t];
                a.x += x.x; a.y += x.y; a.z += x.z; a.w += x.w;
            }
            ((float4*)(vsum + (size_t)b * D_ + (size_t)s * 64))[t] = a;
        }
    } else if (bx == 32) {
        // zero the 4*1024 atomic accumulator G
        float4 z = make_float4(0.f, 0.f, 0.f, 0.f);
        #pragma unroll
        for (int i = 0; i < 4; ++i) ((float4*)G)[i * 256 + t] = z;
    } else {
        int r  = bx - 33;            // atten row, 0..16383
        int i  = r >> 10;            // 0..15
        int qi = r & 1023;
        float val = (mask[((i & 1) << 10) + qi] != 0) ? INV_L : 0.f;
        ((float4*)(atten + (size_t)r * L_))[t] = make_float4(val, val, val, val);
    }
}

// ---- K2 (fused vproj+fc): block = one 32-row m-chunk. ----------------------
// Phase 1: S[b, m0..m0+32) = vsum[b,:] . wv[m,:] + L*bv[m]  -> LDS
// Phase 2: G[2b+p][j] += sum_mm fcw[j, m0+mm] * S[b][mm]  (atomicAdd)
__global__ void __launch_bounds__(256) k_fused(const float* __restrict__ vsum,
                                               const float* __restrict__ wv,
                                               const float* __restrict__ bv,
                                               const float* __restrict__ fcw,
                                               float* __restrict__ G) {
    __shared__ float Sl[2][32];
    int chunk = blockIdx.x;          // 0..383
    int m0    = chunk * 32;
    int p     = (chunk / 48) & 1;    // head parity (1536/32 = 48 chunks/head)
    int t = threadIdx.x, wid = t >> 6, lane = t & 63;
    const float4* v0 = (const float4*)vsum;
    const float4* v1 = (const float4*)(vsum + D_);

    // phase 1: 4 waves x 8 m-rows each
    for (int i = 0; i < 8; ++i) {
        int ml = wid * 8 + i;
        const float4* row = (const float4*)(wv + (size_t)(m0 + ml) * D_);
        float a0 = 0.f, a1 = 0.f;
        #pragma unroll
        for (int it = 0; it < 4; ++it) {        // 256 float4s / 64 lanes
            int c = it * 64 + lane;
            float4 w4 = row[c];
            float4 s0 = v0[c];
            float4 s1 = v1[c];
            a0 += w4.x*s0.x + w4.y*s0.y + w4.z*s0.z + w4.w*s0.w;
            a1 += w4.x*s1.x + w4.y*s1.y + w4.z*s1.z + w4.w*s1.w;
        }
        #pragma unroll
        for (int off = 32; off; off >>= 1) {
            a0 += __shfl_down(a0, off);
            a1 += __shfl_down(a1, off);
        }
        if (lane == 0) {
            float bb = bv[m0 + ml] * (float)L_;
            Sl[0][ml] = a0 + bb;
            Sl[1][ml] = a1 + bb;
        }
    }
    __syncthreads();

    // phase 2: wave covers 8 j per iter (8 lanes per j, 128 B per j-segment)
    int sub = lane >> 3;             // j offset within group of 8
    int f4  = lane & 7;              // float4 index within 32-float chunk
    float4 s0 = *(const float4*)&Sl[0][f4 * 4];
    float4 s1 = *(const float4*)&Sl[1][f4 * 4];
    const float* base = fcw + m0 + (size_t)f4 * 4;
    #pragma unroll 4
    for (int it = 0; it < 32; ++it) {
        int j = wid * 256 + it * 8 + sub;
        float4 w4 = *(const float4*)(base + (size_t)j * HDV_);
        float d0 = w4.x*s0.x + w4.y*s0.y + w4.z*s0.z + w4.w*s0.w;
        float d1 = w4.x*s1.x + w4.y*s1.y + w4.z*s1.z + w4.w*s1.w;
        d0 += __shfl_xor(d0, 1); d1 += __shfl_xor(d1, 1);
        d0 += __shfl_xor(d0, 2); d1 += __shfl_xor(d1, 2);
        d0 += __shfl_xor(d0, 4); d1 += __shfl_xor(d1, 4);
        if (f4 == 0) {
            atomicAdd(&G[(size_t)p * D_ + j],       d0);   // b=0
            atomicAdd(&G[(size_t)(2 + p) * D_ + j], d1);   // b=1
        }
    }
}

// ---- K3: out = LayerNorm(q + (m0*G[b,0] + m1*G[b,1]) / L) ------------------
__global__ void __launch_bounds__(256) k_ln(const float* __restrict__ qin,
                                            const int* __restrict__ mask,
                                            const float* __restrict__ G,
                                            const float* __restrict__ lns,
                                            const float* __restrict__ lnb,
                                            float* __restrict__ out) {
    __shared__ float red[8];
    int row = blockIdx.x;            // b*L + q
    int b   = row >> 10;
    int qi  = row & 1023;
    float m0 = (mask[qi]      != 0) ? INV_L : 0.f;
    float m1 = (mask[L_ + qi] != 0) ? INV_L : 0.f;
    const float4* q4 = (const float4*)(qin + (size_t)row * D_);
    const float4* g0 = (const float4*)(G + (size_t)(2 * b) * D_);
    const float4* g1 = (const float4*)(G + (size_t)(2 * b + 1) * D_);
    int t = threadIdx.x;
    float4 a = q4[t], u = g0[t], w = g1[t];
    float4 x;
    x.x = a.x + m0 * u.x + m1 * w.x;
    x.y = a.y + m0 * u.y + m1 * w.y;
    x.z = a.z + m0 * u.z + m1 * w.z;
    x.w = a.w + m0 * u.w + m1 * w.w;
    float s  = x.x + x.y + x.z + x.w;
    float ss = x.x*x.x + x.y*x.y + x.z*x.z + x.w*x.w;
    #pragma unroll
    for (int off = 32; off; off >>= 1) {
        s  += __shfl_down(s, off);
        ss += __shfl_down(ss, off);
    }
    int lane = t & 63, wv = t >> 6;
    if (lane == 0) { red[wv] = s; red[4 + wv] = ss; }
    __syncthreads();
    if (t == 0) {
        float sAll  = red[0] + red[1] + red[2] + red[3];
        float ssAll = red[4] + red[5] + red[6] + red[7];
        float mu  = sAll * INV_L;
        float var = ssAll * INV_L - mu * mu;
        red[0] = mu;
        red[1] = rsqrtf(var + 1e-5f);
    }
    __syncthreads();
    float mu = red[0], inv = red[1];
    float4 sc = ((const float4*)lns)[t];
    float4 bi = ((const float4*)lnb)[t];
    float4 o;
    o.x = (x.x - mu) * inv * sc.x + bi.x;
    o.y = (x.y - mu) * inv * sc.y + bi.y;
    o.z = (x.z - mu) * inv * sc.z + bi.z;
    o.w = (x.w - mu) * inv * sc.w + bi.w;
    ((float4*)(out + (size_t)row * D_))[t] = o;
}

extern "C" void kernel_launch(void* const* d_in, const int* in_sizes, int n_in,
                              void* d_out, int out_size, void* d_ws, size_t ws_size,
                              hipStream_t stream) {
    const float* q    = (const float*)d_in[0];
    const float* v    = (const float*)d_in[2];
    const int*   mask = (const int*)d_in[3];
    const float* wv   = (const float*)d_in[8];   // w_vs_w
    const float* bv   = (const float*)d_in[9];   // w_vs_b
    const float* fcw  = (const float*)d_in[10];  // fc_w
    const float* lns  = (const float*)d_in[11];
    const float* lnb  = (const float*)d_in[12];

    float* out   = (float*)d_out;
    float* atten = out + (size_t)B_ * L_ * D_;

    float* ws   = (float*)d_ws;
    float* vsum = ws;
    float* G    = ws + 26624;

    k1      <<<33 + 16384, 256, 0, stream>>>(v, vsum, mask, atten, G);
    k_fused <<<HDV_ / 32,  256, 0, stream>>>(vsum, wv, bv, fcw, G);
    k_ln    <<<B_ * L_,    256, 0, stream>>>(q, mask, G, lns, lnb, out);
}

// Round 13
// 48.432 us; speedup vs baseline: 1.2008x; 1.2008x over previous
//
#include <hip/hip_runtime.h>
#include <hip/hip_bf16.h>

#define B_   2
#define L_   1024
#define D_   1024
#define H_   8
#define DV_  1536
#define HDV_ 12288          // H_*DV_
#define INV_L (1.0f/1024.0f)

// ws layout (floats):
//   vsum : [0, 2048)         2*1024 column sums of v
//   G    : [26624, 30720)    4*1024  order: b0p0, b0p1, b1p0, b1p1 (atomic acc)

// ---- K1: blocks [0,32)=vsum; bx==32: zero G; [33,33+16384)=atten rows -----
__global__ void __launch_bounds__(256) k1(const float* __restrict__ v,
                                          float* __restrict__ vsum,
                                          const int* __restrict__ mask,
                                          float* __restrict__ atten,
                                          float* __restrict__ G) {
    int bx = blockIdx.x, t = threadIdx.x;
    if (bx < 32) {
        __shared__ float4 lds[16][16];
        int b  = bx >> 4;            // batch
        int s  = bx & 15;            // 64-column strip
        int c4 = t & 15;             // float4 column within strip
        int rg = t >> 4;             // 16 row-groups of 64 rows
        const float4* vp = (const float4*)(v + (size_t)b * L_ * D_)
                           + (size_t)s * 16 + c4;
        float4 acc = make_float4(0.f, 0.f, 0.f, 0.f);
        #pragma unroll 8
        for (int r = 0; r < 64; ++r) {
            float4 x = vp[(size_t)(rg * 64 + r) * (D_ / 4)];
            acc.x += x.x; acc.y += x.y; acc.z += x.z; acc.w += x.w;
        }
        lds[rg][c4] = acc;
        __syncthreads();
        if (t < 16) {                // t = c4
            float4 a = make_float4(0.f, 0.f, 0.f, 0.f);
            #pragma unroll
            for (int g = 0; g < 16; ++g) {
                float4 x = lds[g][t];
                a.x += x.x; a.y += x.y; a.z += x.z; a.w += x.w;
            }
            ((float4*)(vsum + (size_t)b * D_ + (size_t)s * 64))[t] = a;
        }
    } else if (bx == 32) {
        float4 z = make_float4(0.f, 0.f, 0.f, 0.f);
        #pragma unroll
        for (int i = 0; i < 4; ++i) ((float4*)G)[i * 256 + t] = z;
    } else {
        int r  = bx - 33;            // atten row, 0..16383
        int i  = r >> 10;            // 0..15
        int qi = r & 1023;
        float val = (mask[((i & 1) << 10) + qi] != 0) ? INV_L : 0.f;
        ((float4*)(atten + (size_t)r * L_))[t] = make_float4(val, val, val, val);
    }
}

// ---- K2 (fused vproj+fc), MLP-redesigned. Block = one 32-row m-chunk. -----
// Phase 1: S[b, m0+ml] = vsum[b,:].wv[m0+ml,:] + L*bv[m0+ml] -> LDS (2-row ILP)
// Phase 2: thread t handles j = jj*256+t (jj<4): 8 contiguous float4 loads of
//          fcw[j, m0..m0+32) (one 128B line), dot with LDS S, atomicAdd to G.
__global__ void __launch_bounds__(256) k_fused(const float* __restrict__ vsum,
                                               const float* __restrict__ wv,
                                               const float* __restrict__ bv,
                                               const float* __restrict__ fcw,
                                               float* __restrict__ G) {
    __shared__ float Sl[2][32];
    int chunk = blockIdx.x;          // 0..383
    int m0    = chunk * 32;
    int p     = (chunk / 48) & 1;    // head parity (1536/32 = 48 chunks/head)
    int t = threadIdx.x, wid = t >> 6, lane = t & 63;
    const float4* v0 = (const float4*)vsum;
    const float4* v1 = (const float4*)(vsum + D_);

    // phase 1: 4 waves x 8 m-rows, 2 rows interleaved per pass (8 loads in flight)
    #pragma unroll
    for (int i = 0; i < 4; ++i) {
        int ml = wid * 8 + i * 2;
        const float4* r0 = (const float4*)(wv + (size_t)(m0 + ml)     * D_);
        const float4* r1 = (const float4*)(wv + (size_t)(m0 + ml + 1) * D_);
        float a00 = 0.f, a01 = 0.f, a10 = 0.f, a11 = 0.f;
        #pragma unroll
        for (int it = 0; it < 4; ++it) {        // 256 float4s / 64 lanes
            int c = it * 64 + lane;
            float4 wa = r0[c], wb = r1[c];
            float4 s0 = v0[c], s1 = v1[c];
            a00 += wa.x*s0.x + wa.y*s0.y + wa.z*s0.z + wa.w*s0.w;
            a01 += wa.x*s1.x + wa.y*s1.y + wa.z*s1.z + wa.w*s1.w;
            a10 += wb.x*s0.x + wb.y*s0.y + wb.z*s0.z + wb.w*s0.w;
            a11 += wb.x*s1.x + wb.y*s1.y + wb.z*s1.z + wb.w*s1.w;
        }
        #pragma unroll
        for (int off = 32; off; off >>= 1) {
            a00 += __shfl_down(a00, off);
            a01 += __shfl_down(a01, off);
            a10 += __shfl_down(a10, off);
            a11 += __shfl_down(a11, off);
        }
        if (lane == 0) {
            float bb0 = bv[m0 + ml]     * (float)L_;
            float bb1 = bv[m0 + ml + 1] * (float)L_;
            Sl[0][ml]     = a00 + bb0;
            Sl[1][ml]     = a01 + bb0;
            Sl[0][ml + 1] = a10 + bb1;
            Sl[1][ml + 1] = a11 + bb1;
        }
    }
    __syncthreads();

    // phase 2: per-thread j, contiguous 128B fcw segment, high MLP
    const float4* S40 = (const float4*)&Sl[0][0];
    const float4* S41 = (const float4*)&Sl[1][0];
    #pragma unroll
    for (int jj = 0; jj < 4; ++jj) {
        int j = jj * 256 + t;
        const float4* fj = (const float4*)(fcw + (size_t)j * HDV_ + m0);
        float d0 = 0.f, d1 = 0.f;
        #pragma unroll
        for (int g = 0; g < 8; ++g) {
            float4 w4 = fj[g];
            float4 s0 = S40[g];      // LDS broadcast (uniform addr)
            float4 s1 = S41[g];
            d0 += w4.x*s0.x + w4.y*s0.y + w4.z*s0.z + w4.w*s0.w;
            d1 += w4.x*s1.x + w4.y*s1.y + w4.z*s1.z + w4.w*s1.w;
        }
        atomicAdd(&G[(size_t)p * D_ + j],       d0);   // b=0
        atomicAdd(&G[(size_t)(2 + p) * D_ + j], d1);   // b=1
    }
}

// ---- K3: out = LayerNorm(q + (m0*G[b,0] + m1*G[b,1]) / L) ------------------
__global__ void __launch_bounds__(256) k_ln(const float* __restrict__ qin,
                                            const int* __restrict__ mask,
                                            const float* __restrict__ G,
                                            const float* __restrict__ lns,
                                            const float* __restrict__ lnb,
                                            float* __restrict__ out) {
    __shared__ float red[8];
    int row = blockIdx.x;            // b*L + q
    int b   = row >> 10;
    int qi  = row & 1023;
    float m0 = (mask[qi]      != 0) ? INV_L : 0.f;
    float m1 = (mask[L_ + qi] != 0) ? INV_L : 0.f;
    const float4* q4 = (const float4*)(qin + (size_t)row * D_);
    const float4* g0 = (const float4*)(G + (size_t)(2 * b) * D_);
    const float4* g1 = (const float4*)(G + (size_t)(2 * b + 1) * D_);
    int t = threadIdx.x;
    float4 a = q4[t], u = g0[t], w = g1[t];
    float4 x;
    x.x = a.x + m0 * u.x + m1 * w.x;
    x.y = a.y + m0 * u.y + m1 * w.y;
    x.z = a.z + m0 * u.z + m1 * w.z;
    x.w = a.w + m0 * u.w + m1 * w.w;
    float s  = x.x + x.y + x.z + x.w;
    float ss = x.x*x.x + x.y*x.y + x.z*x.z + x.w*x.w;
    #pragma unroll
    for (int off = 32; off; off >>= 1) {
        s  += __shfl_down(s, off);
        ss += __shfl_down(ss, off);
    }
    int lane = t & 63, wv = t >> 6;
    if (lane == 0) { red[wv] = s; red[4 + wv] = ss; }
    __syncthreads();
    if (t == 0) {
        float sAll  = red[0] + red[1] + red[2] + red[3];
        float ssAll = red[4] + red[5] + red[6] + red[7];
        float mu  = sAll * INV_L;
        float var = ssAll * INV_L - mu * mu;
        red[0] = mu;
        red[1] = rsqrtf(var + 1e-5f);
    }
    __syncthreads();
    float mu = red[0], inv = red[1];
    float4 sc = ((const float4*)lns)[t];
    float4 bi = ((const float4*)lnb)[t];
    float4 o;
    o.x = (x.x - mu) * inv * sc.x + bi.x;
    o.y = (x.y - mu) * inv * sc.y + bi.y;
    o.z = (x.z - mu) * inv * sc.z + bi.z;
    o.w = (x.w - mu) * inv * sc.w + bi.w;
    ((float4*)(out + (size_t)row * D_))[t] = o;
}

extern "C" void kernel_launch(void* const* d_in, const int* in_sizes, int n_in,
                              void* d_out, int out_size, void* d_ws, size_t ws_size,
                              hipStream_t stream) {
    const float* q    = (const float*)d_in[0];
    const float* v    = (const float*)d_in[2];
    const int*   mask = (const int*)d_in[3];
    const float* wv   = (const float*)d_in[8];   // w_vs_w
    const float* bv   = (const float*)d_in[9];   // w_vs_b
    const float* fcw  = (const float*)d_in[10];  // fc_w
    const float* lns  = (const float*)d_in[11];
    const float* lnb  = (const float*)d_in[12];

    float* out   = (float*)d_out;
    float* atten = out + (size_t)B_ * L_ * D_;

    float* ws   = (float*)d_ws;
    float* vsum = ws;
    float* G    = ws + 26624;

    k1      <<<33 + 16384, 256, 0, stream>>>(v, vsum, mask, atten, G);
    k_fused <<<HDV_ / 32,  256, 0, stream>>>(vsum, wv, bv, fcw, G);
    k_ln    <<<B_ * L_,    256, 0, stream>>>(q, mask, G, lns, lnb, out);
}

// Round 14
// 41.286 us; speedup vs baseline: 1.4086x; 1.1731x over previous
//
#include <hip/hip_runtime.h>
#include <hip/hip_bf16.h>

#define B_   2
#define L_   1024
#define D_   1024
#define H_   8
#define DV_  1536
#define HDV_ 12288          // H_*DV_
#define INV_L (1.0f/1024.0f)

// ws layout (floats):
//   vsum : [0, 2048)         2*1024 column sums of v
//   S    : [2048, 26624)     2*12288
//   G    : [26624, 30720)    4*1024   order: b0p0, b0p1, b1p0, b1p1

// ---- K1: blocks [0,32) = direct vsum; blocks [32, 32+16384) = atten rows
__global__ void __launch_bounds__(256) k1(const float* __restrict__ v,
                                          float* __restrict__ vsum,
                                          const int* __restrict__ mask,
                                          float* __restrict__ atten) {
    int bx = blockIdx.x, t = threadIdx.x;
    if (bx < 32) {
        __shared__ float4 lds[16][16];
        int b  = bx >> 4;            // batch
        int s  = bx & 15;            // 64-column strip
        int c4 = t & 15;             // float4 column within strip
        int rg = t >> 4;             // 16 row-groups of 64 rows
        const float4* vp = (const float4*)(v + (size_t)b * L_ * D_)
                           + (size_t)s * 16 + c4;
        float4 acc = make_float4(0.f, 0.f, 0.f, 0.f);
        #pragma unroll 8
        for (int r = 0; r < 64; ++r) {
            float4 x = vp[(size_t)(rg * 64 + r) * (D_ / 4)];
            acc.x += x.x; acc.y += x.y; acc.z += x.z; acc.w += x.w;
        }
        lds[rg][c4] = acc;
        __syncthreads();
        if (t < 16) {                // t = c4
            float4 a = make_float4(0.f, 0.f, 0.f, 0.f);
            #pragma unroll
            for (int g = 0; g < 16; ++g) {
                float4 x = lds[g][t];
                a.x += x.x; a.y += x.y; a.z += x.z; a.w += x.w;
            }
            ((float4*)(vsum + (size_t)b * D_ + (size_t)s * 64))[t] = a;
        }
    } else {
        int r  = bx - 32;            // atten row, 0..16383
        int i  = r >> 10;            // 0..15
        int qi = r & 1023;
        float val = (mask[((i & 1) << 10) + qi] != 0) ? INV_L : 0.f;
        ((float4*)(atten + (size_t)r * L_))[t] = make_float4(val, val, val, val);
    }
}

// ---- K2: S[b,m] = vsum[b,:] . w_vs_w[m,:] + L*b_vs[m]  (one wave per m) ----
__global__ void __launch_bounds__(256) k_vproj(const float* __restrict__ vsum,
                                               const float* __restrict__ wv,
                                               const float* __restrict__ bv,
                                               float* __restrict__ S) {
    int gid  = blockIdx.x * 256 + threadIdx.x;
    int m    = gid >> 6;
    int lane = threadIdx.x & 63;
    const float4* row = (const float4*)(wv + (size_t)m * D_);
    const float4* v0  = (const float4*)vsum;
    const float4* v1  = (const float4*)(vsum + D_);
    float a0 = 0.f, a1 = 0.f;
    #pragma unroll
    for (int it = 0; it < 4; ++it) {            // D_/4 = 256 float4s / 64 lanes
        int c = it * 64 + lane;
        float4 w4 = row[c];
        float4 s0 = v0[c];
        float4 s1 = v1[c];
        a0 += w4.x*s0.x + w4.y*s0.y + w4.z*s0.z + w4.w*s0.w;
        a1 += w4.x*s1.x + w4.y*s1.y + w4.z*s1.z + w4.w*s1.w;
    }
    #pragma unroll
    for (int off = 32; off; off >>= 1) {
        a0 += __shfl_down(a0, off);
        a1 += __shfl_down(a1, off);
    }
    if (lane == 0) {
        float bb = bv[m] * (float)L_;
        S[m]        = a0 + bb;
        S[HDV_ + m] = a1 + bb;
    }
}

// ---- K3: G[b,p,j] = sum_{h%2==p} sum_d S[b,h*DV+d]*fc_w[j,h*DV+d] ----------
// One 256-thread block per j.
__global__ void __launch_bounds__(256) k_fc(const float* __restrict__ S,
                                            const float* __restrict__ fcw,
                                            float* __restrict__ G) {
    __shared__ float red[16];
    int j = blockIdx.x, t = threadIdx.x;
    const float4* row = (const float4*)(fcw + (size_t)j * HDV_);
    const float4* S0  = (const float4*)S;
    const float4* S1  = (const float4*)(S + HDV_);
    float g00 = 0.f, g01 = 0.f, g10 = 0.f, g11 = 0.f;
    #pragma unroll
    for (int it = 0; it < 12; ++it) {           // HDV_/4 = 3072 float4s / 256 thr
        int t4 = it * 256 + t;
        int p  = (t4 / 384) & 1;                // 384 = DV_/4, float4 never straddles
        float4 w4 = row[t4];
        float4 s0 = S0[t4];
        float4 s1 = S1[t4];
        float d0 = w4.x*s0.x + w4.y*s0.y + w4.z*s0.z + w4.w*s0.w;
        float d1 = w4.x*s1.x + w4.y*s1.y + w4.z*s1.z + w4.w*s1.w;
        if (p) { g01 += d0; g11 += d1; } else { g00 += d0; g10 += d1; }
    }
    #pragma unroll
    for (int off = 32; off; off >>= 1) {
        g00 += __shfl_down(g00, off);
        g01 += __shfl_down(g01, off);
        g10 += __shfl_down(g10, off);
        g11 += __shfl_down(g11, off);
    }
    int lane = t & 63, w = t >> 6;
    if (lane == 0) {
        red[w * 4 + 0] = g00; red[w * 4 + 1] = g01;
        red[w * 4 + 2] = g10; red[w * 4 + 3] = g11;
    }
    __syncthreads();
    if (t < 4) {
        float x = red[t] + red[4 + t] + red[8 + t] + red[12 + t];
        G[(size_t)t * D_ + j] = x;              // t: 0=b0p0 1=b0p1 2=b1p0 3=b1p1
    }
}

// ---- K4: out = LayerNorm(q + (m0*G[b,0] + m1*G[b,1]) / L) ------------------
__global__ void __launch_bounds__(256) k_ln(const float* __restrict__ qin,
                                            const int* __restrict__ mask,
                                            const float* __restrict__ G,
                                            const float* __restrict__ lns,
                                            const float* __restrict__ lnb,
                                            float* __restrict__ out) {
    __shared__ float red[8];
    int row = blockIdx.x;            // b*L + q
    int b   = row >> 10;
    int qi  = row & 1023;
    float m0 = (mask[qi]      != 0) ? INV_L : 0.f;
    float m1 = (mask[L_ + qi] != 0) ? INV_L : 0.f;
    const float4* q4 = (const float4*)(qin + (size_t)row * D_);
    const float4* g0 = (const float4*)(G + (size_t)(2 * b) * D_);
    const float4* g1 = (const float4*)(G + (size_t)(2 * b + 1) * D_);
    int t = threadIdx.x;
    float4 a = q4[t], u = g0[t], w = g1[t];
    float4 x;
    x.x = a.x + m0 * u.x + m1 * w.x;
    x.y = a.y + m0 * u.y + m1 * w.y;
    x.z = a.z + m0 * u.z + m1 * w.z;
    x.w = a.w + m0 * u.w + m1 * w.w;
    float s  = x.x + x.y + x.z + x.w;
    float ss = x.x*x.x + x.y*x.y + x.z*x.z + x.w*x.w;
    #pragma unroll
    for (int off = 32; off; off >>= 1) {
        s  += __shfl_down(s, off);
        ss += __shfl_down(ss, off);
    }
    int lane = t & 63, wv = t >> 6;
    if (lane == 0) { red[wv] = s; red[4 + wv] = ss; }
    __syncthreads();
    if (t == 0) {
        float sAll  = red[0] + red[1] + red[2] + red[3];
        float ssAll = red[4] + red[5] + red[6] + red[7];
        float mu  = sAll * INV_L;
        float var = ssAll * INV_L - mu * mu;
        red[0] = mu;
        red[1] = rsqrtf(var + 1e-5f);
    }
    __syncthreads();
    float mu = red[0], inv = red[1];
    float4 sc = ((const float4*)lns)[t];
    float4 bi = ((const float4*)lnb)[t];
    float4 o;
    o.x = (x.x - mu) * inv * sc.x + bi.x;
    o.y = (x.y - mu) * inv * sc.y + bi.y;
    o.z = (x.z - mu) * inv * sc.z + bi.z;
    o.w = (x.w - mu) * inv * sc.w + bi.w;
    ((float4*)(out + (size_t)row * D_))[t] = o;
}

extern "C" void kernel_launch(void* const* d_in, const int* in_sizes, int n_in,
                              void* d_out, int out_size, void* d_ws, size_t ws_size,
                              hipStream_t stream) {
    const float* q    = (const float*)d_in[0];
    const float* v    = (const float*)d_in[2];
    const int*   mask = (const int*)d_in[3];
    const float* wv   = (const float*)d_in[8];   // w_vs_w
    const float* bv   = (const float*)d_in[9];   // w_vs_b
    const float* fcw  = (const float*)d_in[10];  // fc_w
    const float* lns  = (const float*)d_in[11];
    const float* lnb  = (const float*)d_in[12];

    float* out   = (float*)d_out;
    float* atten = out + (size_t)B_ * L_ * D_;

    float* ws   = (float*)d_ws;
    float* vsum = ws;
    float* S    = ws + 2048;
    float* G    = ws + 26624;

    k1      <<<32 + 16384, 256, 0, stream>>>(v, vsum, mask, atten);
    k_vproj <<<(HDV_ * 64) / 256, 256, 0, stream>>>(vsum, wv, bv, S);
    k_fc    <<<D_, 256, 0, stream>>>(S, fcw, G);
    k_ln    <<<B_ * L_, 256, 0, stream>>>(q, mask, G, lns, lnb, out);
}